// Round 9
// baseline (551.871 us; speedup 1.0000x reference)
//
#include <hip/hip_runtime.h>
#include <hip/hip_bf16.h>
#include <stdint.h>

// B=4, M=256, N=64, D=512, C=1024
// out[b,m,n,c] = log_softmax_c( tanh(pe[b,m,:] + pd[b,n,:]) . W2[c,:] + b2[c] )
// pe = enc @ W1[:, :D]^T ; pd = dec @ W1[:, D:]^T + b1

typedef __bf16         bf16x8 __attribute__((ext_vector_type(8)));
typedef float          f32x4  __attribute__((ext_vector_type(4)));
typedef unsigned short u16x8  __attribute__((ext_vector_type(8)));

__device__ __forceinline__ unsigned short f2bf(float f) {
  unsigned int u = __float_as_uint(f);
  u += 0x7fffu + ((u >> 16) & 1u);          // RNE
  return (unsigned short)(u >> 16);
}

__device__ __forceinline__ f32x4 mfma16(u16x8 a, u16x8 b, f32x4 c) {
  return __builtin_amdgcn_mfma_f32_16x16x32_bf16(
      __builtin_bit_cast(bf16x8, a), __builtin_bit_cast(bf16x8, b), c, 0, 0, 0);
}

// barrier that does NOT drain vmem (NT stores stay in flight); LDS-safe.
#define LGKM_BAR() do {                                   \
  asm volatile("s_waitcnt lgkmcnt(0)" ::: "memory");      \
  __builtin_amdgcn_s_barrier();                           \
  __builtin_amdgcn_sched_barrier(0);                      \
} while (0)

// ---------------- prep: f32 -> bf16 conversions ----------------
__global__ __launch_bounds__(256) void prep_kernel(
    const float* __restrict__ enc, const float* __restrict__ dec,
    const float* __restrict__ W1,  const float* __restrict__ W2,
    unsigned short* __restrict__ encB, unsigned short* __restrict__ decB,
    unsigned short* __restrict__ W1eB, unsigned short* __restrict__ W1dB,
    unsigned short* __restrict__ W2B)
{
  const int i = blockIdx.x * 256 + threadIdx.x;   // 0 .. 524287
  encB[i] = f2bf(enc[i]);
  W2B[i]  = f2bf(W2[i]);
  if (i < 262144) {                                // W1 is [512][1024]
    const int k = i >> 9, d = i & 511;
    W1eB[i] = f2bf(W1[k * 1024 + d]);
    W1dB[i] = f2bf(W1[k * 1024 + 512 + d]);
  }
  if (i < 131072) decB[i] = f2bf(dec[i]);
}

// ---------------- proj: out[r][c] = sum_d A[r][d]*Wt[c][d] (+bias[c]) ----------------
__global__ __launch_bounds__(256) void proj_kernel(
    const unsigned short* __restrict__ A, const unsigned short* __restrict__ Wt,
    const float* __restrict__ bias, float* __restrict__ out)
{
  const int rtile = blockIdx.x >> 3;
  const int ctile = blockIdx.x & 7;
  const int w = threadIdx.x >> 6;
  const int l = threadIdx.x & 63;
  const int q = l >> 4, ln = l & 15;

  f32x4 acc[4] = {};
  const unsigned short* Ab = A  + (size_t)(rtile * 64 + ln) * 512 + q * 8;
  const unsigned short* Wb = Wt + (size_t)(ctile * 64 + w * 16 + ln) * 512 + q * 8;

#pragma unroll 4
  for (int ks = 0; ks < 16; ++ks) {
    u16x8 bv = *(const u16x8*)(Wb + ks * 32);
#pragma unroll
    for (int rf = 0; rf < 4; ++rf) {
      u16x8 av = *(const u16x8*)(Ab + rf * 16 * 512 + ks * 32);
      acc[rf] = mfma16(av, bv, acc[rf]);
    }
  }
  const int col = ctile * 64 + w * 16 + ln;
  const float bv = bias ? bias[col] : 0.0f;
#pragma unroll
  for (int rf = 0; rf < 4; ++rf)
#pragma unroll
    for (int j = 0; j < 4; ++j)
      out[(size_t)(rtile * 64 + rf * 16 + q * 4 + j) * 512 + col] = acc[rf][j] + bv;
}

// ---------------- joint: fused tanh-GEMM + bias + log_softmax ----------------
// grid = 512 blocks (2 rounds), block = 512 threads (8 waves), 2 m-tiles/block.
// Block bid: b = bid>>7, m = (bid&127)*2 + t, t = 0..1. Each tile: 64 rows x 1024 cols.
// Wave w: all 64 rows x cols [w*128, w*128+128). acc[4][8] f32x4 = 128 f32/thread.
// W2 panel L2-residency amortized over 2 tiles; stores(t) issued AFTER gen(t+1)
// so gen's vmcnt waits don't drain them -> stores overlap GEMM(t+1).
__global__ __launch_bounds__(512, 2) void joint_kernel(
    const float* __restrict__ pe, const float* __restrict__ pd,
    const unsigned short* __restrict__ W2B, const float* __restrict__ b2,
    float* __restrict__ out)
{
  __shared__ unsigned short A_sh[64 * 512];   // 64 KiB, XOR-swizzled bf16 tile
  __shared__ float2 red[64][9];               // per-row, per-wave (max, sumexp), padded
  __shared__ float  lse_sh[64];

  const int bid = blockIdx.x;          // 0..511
  const int b   = bid >> 7;
  const int m0  = (bid & 127) << 1;
  const int tid = threadIdx.x;
  const int w = tid >> 6, l = tid & 63;
  const int q = l >> 4, ln = l & 15;

  const unsigned short* Wb = W2B + (size_t)(w * 128 + ln) * 512 + q * 8;  // + cf*8192 + ks*32
  float b2v[8];
#pragma unroll
  for (int cf = 0; cf < 8; ++cf) b2v[cf] = b2[w * 128 + cf * 16 + ln];

  // gen: A[n][d] = tanh(pe[m,d] + pd[n,d]) into swizzled LDS.
  // wave w owns rows w*8..w*8+7; lane l owns d = l*8..l*8+7 (coalesced).
  auto gen = [&](int m) {
    const int p = (b << 8) | m;
    const float* per = pe + (size_t)p * 512 + l * 8;
    const float4 pe0 = *(const float4*)(per);
    const float4 pe1 = *(const float4*)(per + 4);
#pragma unroll
    for (int r = 0; r < 8; ++r) {
      const int n = (w << 3) | r;
      const float* pdr = pd + (size_t)((b << 6) | n) * 512 + l * 8;
      const float4 q0 = *(const float4*)(pdr);
      const float4 q1 = *(const float4*)(pdr + 4);
      float x[8] = {pe0.x + q0.x, pe0.y + q0.y, pe0.z + q0.z, pe0.w + q0.w,
                    pe1.x + q1.x, pe1.y + q1.y, pe1.z + q1.z, pe1.w + q1.w};
      u16x8 pk;
#pragma unroll
      for (int e = 0; e < 8; ++e) {
        const float ex = __expf(2.0f * x[e]);                    // tanh = 1 - 2/(e^2x+1)
        const float tv = 1.0f - 2.0f * __builtin_amdgcn_rcpf(ex + 1.0f);
        pk[e] = f2bf(tv);
      }
      *(u16x8*)((char*)A_sh + n * 1024 + ((l ^ (n & 7)) << 4)) = pk;
    }
  };

  gen(m0);
  LGKM_BAR();

#pragma unroll 1
  for (int t = 0; t < 2; ++t) {
    // ---- GEMM tile t: wave w owns cols [w*128, w*128+128), rows 0..63 ----
    f32x4 acc[4][8];
#pragma unroll
    for (int rf = 0; rf < 4; ++rf)
#pragma unroll
      for (int cf = 0; cf < 8; ++cf) acc[rf][cf] = (f32x4){0.f, 0.f, 0.f, 0.f};

    const char* Abase = (const char*)A_sh + ln * 1024;   // + rf*16384, row = rf*16+ln
    const int xr = ln & 7;

    for (int ks = 0; ks < 16; ++ks) {
      u16x8 av[4];
#pragma unroll
      for (int rf = 0; rf < 4; ++rf)
        av[rf] = *(const u16x8*)(Abase + rf * 16384 + (((ks * 4 + q) ^ xr) << 4));
#pragma unroll
      for (int cfh = 0; cfh < 2; ++cfh) {
        u16x8 bv[4];
#pragma unroll
        for (int cc = 0; cc < 4; ++cc)
          bv[cc] = *(const u16x8*)(Wb + (cfh * 4 + cc) * 8192 + ks * 32);
#pragma unroll
        for (int rf = 0; rf < 4; ++rf)
#pragma unroll
          for (int cc = 0; cc < 4; ++cc)
            acc[rf][cfh * 4 + cc] = mfma16(av[rf], bv[cc], acc[rf][cfh * 4 + cc]);
      }
    }
    LGKM_BAR();   // A_sh reads done -> may be overwritten by gen(t+1)

    // ---- epilogue: + b2, per-wave partial (max,sumexp) over 128 cols ----
#pragma unroll
    for (int rf = 0; rf < 4; ++rf)
#pragma unroll
      for (int cf = 0; cf < 8; ++cf)
#pragma unroll
        for (int j = 0; j < 4; ++j) acc[rf][cf][j] += b2v[cf];

    {
      float mx[4][4], sm[4][4];
#pragma unroll
      for (int rf = 0; rf < 4; ++rf)
#pragma unroll
        for (int j = 0; j < 4; ++j) {
          float m = acc[rf][0][j];
#pragma unroll
          for (int cf = 1; cf < 8; ++cf) m = fmaxf(m, acc[rf][cf][j]);
          mx[rf][j] = m;
        }
#pragma unroll
      for (int o = 1; o < 16; o <<= 1)
#pragma unroll
        for (int rf = 0; rf < 4; ++rf)
#pragma unroll
          for (int j = 0; j < 4; ++j)
            mx[rf][j] = fmaxf(mx[rf][j], __shfl_xor(mx[rf][j], o));
#pragma unroll
      for (int rf = 0; rf < 4; ++rf)
#pragma unroll
        for (int j = 0; j < 4; ++j) {
          float s = 0.f;
#pragma unroll
          for (int cf = 0; cf < 8; ++cf) s += __expf(acc[rf][cf][j] - mx[rf][j]);
          sm[rf][j] = s;
        }
#pragma unroll
      for (int o = 1; o < 16; o <<= 1)
#pragma unroll
        for (int rf = 0; rf < 4; ++rf)
#pragma unroll
          for (int j = 0; j < 4; ++j)
            sm[rf][j] += __shfl_xor(sm[rf][j], o);
      if (ln == 0) {
#pragma unroll
        for (int rf = 0; rf < 4; ++rf)
#pragma unroll
          for (int j = 0; j < 4; ++j)
            red[rf * 16 + q * 4 + j][w] = make_float2(mx[rf][j], sm[rf][j]);
      }
    }
    LGKM_BAR();

    // merge the 8 wave-partials: thread tid<64 handles row tid
    if (tid < 64) {
      float m = red[tid][0].x;
#pragma unroll
      for (int ww = 1; ww < 8; ++ww) m = fmaxf(m, red[tid][ww].x);
      float s = 0.f;
#pragma unroll
      for (int ww = 0; ww < 8; ++ww) s += red[tid][ww].y * __expf(red[tid][ww].x - m);
      lse_sh[tid] = m + __logf(s);
    }
    LGKM_BAR();

    // gen(t+1) BEFORE stores(t): its vmcnt waits precede the stores in program
    // order, so the stores stay in flight and drain under GEMM(t+1).
    if (t == 0) gen(m0 + 1);

    // ---- nontemporal stores for tile t ----
    const int p = (b << 8) | (m0 + t);
    float* outb = out + (size_t)p * 65536 + w * 128 + ln;
#pragma unroll
    for (int rf = 0; rf < 4; ++rf)
#pragma unroll
      for (int j = 0; j < 4; ++j) {
        const int row = rf * 16 + q * 4 + j;
        const float lse = lse_sh[row];
        float* orow = outb + (size_t)row * 1024;
#pragma unroll
        for (int cf = 0; cf < 8; ++cf)
          __builtin_nontemporal_store(acc[rf][cf][j] - lse, orow + cf * 16);
      }

    if (t == 0) LGKM_BAR();   // A_sh(t=1) + lse_sh protection before next GEMM
  }
}

extern "C" void kernel_launch(void* const* d_in, const int* in_sizes, int n_in,
                              void* d_out, int out_size, void* d_ws, size_t ws_size,
                              hipStream_t stream) {
  (void)in_sizes; (void)n_in; (void)out_size; (void)ws_size;
  const float* enc = (const float*)d_in[0];
  const float* dec = (const float*)d_in[1];
  const float* W1  = (const float*)d_in[2];
  const float* b1  = (const float*)d_in[3];
  const float* W2  = (const float*)d_in[4];
  const float* b2  = (const float*)d_in[5];
  float* out = (float*)d_out;

  char* ws = (char*)d_ws;
  unsigned short* encB = (unsigned short*)(ws + 0);        // 1 MiB   (524288 el)
  unsigned short* decB = (unsigned short*)(ws + 1048576);  // 256 KiB (131072 el)
  unsigned short* W1eB = (unsigned short*)(ws + 1310720);  // 512 KiB (262144 el)
  unsigned short* W1dB = (unsigned short*)(ws + 1835008);  // 512 KiB (262144 el)
  unsigned short* W2B  = (unsigned short*)(ws + 2359296);  // 1 MiB   (524288 el)
  float*          pe   = (float*)(ws + 3407872);           // 2 MiB  [1024][512]
  float*          pd   = (float*)(ws + 5505024);           // 512 KiB [256][512]

  prep_kernel<<<2048, 256, 0, stream>>>(enc, dec, W1, W2, encB, decB, W1eB, W1dB, W2B);
  proj_kernel<<<128, 256, 0, stream>>>(encB, W1eB, nullptr, pe);   // pe: 1024x512
  proj_kernel<<< 32, 256, 0, stream>>>(decB, W1dB, b1,      pd);   // pd:  256x512
  joint_kernel<<<512, 512, 0, stream>>>(pe, pd, W2B, b2, out);
}

// Round 11
// 224.708 us; speedup vs baseline: 2.4559x; 2.4559x over previous
//
#include <hip/hip_runtime.h>
#include <hip/hip_bf16.h>
#include <stdint.h>

// B=4, M=256, N=64, D=512, C=1024
// out[b,m,n,c] = log_softmax_c( tanh(pe[b,m,:] + pd[b,n,:]) . W2[c,:] + b2[c] )
// pe = enc @ W1[:, :D]^T ; pd = dec @ W1[:, D:]^T + b1
// log_softmax computed WITHOUT the max pass (shift-invariant; logits bounded
// by ||W2[c,:]||_1 + |b2| ~ 18 -> sum(exp) <= 1024*e^18 ~ 2^36.5, f32-safe).

typedef __bf16         bf16x8 __attribute__((ext_vector_type(8)));
typedef float          f32x4  __attribute__((ext_vector_type(4)));
typedef unsigned short u16x8  __attribute__((ext_vector_type(8)));

__device__ __forceinline__ unsigned short f2bf(float f) {
  unsigned int u = __float_as_uint(f);
  u += 0x7fffu + ((u >> 16) & 1u);          // RNE
  return (unsigned short)(u >> 16);
}

__device__ __forceinline__ f32x4 mfma16(u16x8 a, u16x8 b, f32x4 c) {
  return __builtin_amdgcn_mfma_f32_16x16x32_bf16(
      __builtin_bit_cast(bf16x8, a), __builtin_bit_cast(bf16x8, b), c, 0, 0, 0);
}

// ---------------- prep: f32 -> bf16 conversions ----------------
__global__ __launch_bounds__(256) void prep_kernel(
    const float* __restrict__ enc, const float* __restrict__ dec,
    const float* __restrict__ W1,  const float* __restrict__ W2,
    unsigned short* __restrict__ encB, unsigned short* __restrict__ decB,
    unsigned short* __restrict__ W1eB, unsigned short* __restrict__ W1dB,
    unsigned short* __restrict__ W2B)
{
  const int i = blockIdx.x * 256 + threadIdx.x;   // 0 .. 524287
  encB[i] = f2bf(enc[i]);
  W2B[i]  = f2bf(W2[i]);
  if (i < 262144) {                                // W1 is [512][1024]
    const int k = i >> 9, d = i & 511;
    W1eB[i] = f2bf(W1[k * 1024 + d]);
    W1dB[i] = f2bf(W1[k * 1024 + 512 + d]);
  }
  if (i < 131072) decB[i] = f2bf(dec[i]);
}

// ---------------- proj: out[r][c] = sum_d A[r][d]*Wt[c][d] (+bias[c]) ----------------
__global__ __launch_bounds__(256) void proj_kernel(
    const unsigned short* __restrict__ A, const unsigned short* __restrict__ Wt,
    const float* __restrict__ bias, float* __restrict__ out)
{
  const int rtile = blockIdx.x >> 3;
  const int ctile = blockIdx.x & 7;
  const int w = threadIdx.x >> 6;
  const int l = threadIdx.x & 63;
  const int q = l >> 4, ln = l & 15;

  f32x4 acc[4] = {};
  const unsigned short* Ab = A  + (size_t)(rtile * 64 + ln) * 512 + q * 8;
  const unsigned short* Wb = Wt + (size_t)(ctile * 64 + w * 16 + ln) * 512 + q * 8;

#pragma unroll 4
  for (int ks = 0; ks < 16; ++ks) {
    u16x8 bv = *(const u16x8*)(Wb + ks * 32);
#pragma unroll
    for (int rf = 0; rf < 4; ++rf) {
      u16x8 av = *(const u16x8*)(Ab + rf * 16 * 512 + ks * 32);
      acc[rf] = mfma16(av, bv, acc[rf]);
    }
  }
  const int col = ctile * 64 + w * 16 + ln;
  const float bv = bias ? bias[col] : 0.0f;
#pragma unroll
  for (int rf = 0; rf < 4; ++rf)
#pragma unroll
    for (int j = 0; j < 4; ++j)
      out[(size_t)(rtile * 64 + rf * 16 + q * 4 + j) * 512 + col] = acc[rf][j] + bv;
}

// ---------------- joint: fused tanh-GEMM + bias + log_softmax (no-max) ----------------
// grid = B*M = 1024 blocks, block = 1024 threads (16 waves).
// Wave w: all 64 rows x cols [w*64, w*64+64). acc = 4x4 f32x4 = 64 f32/thread.
__global__ __launch_bounds__(1024) void joint_kernel(
    const float* __restrict__ pe, const float* __restrict__ pd,
    const unsigned short* __restrict__ W2B, const float* __restrict__ b2,
    float* __restrict__ out)
{
  __shared__ unsigned short A_sh[64 * 512];   // 64 KiB, XOR-swizzled bf16 tile
  __shared__ float red[64][17];               // per-row, per-wave sum2exp (padded)
  __shared__ float lse_sh[64];

  const int blk = blockIdx.x;            // b*256 + m
  const int b   = blk >> 8;
  const int tid = threadIdx.x;
  const int w = tid >> 6, l = tid & 63;
  const int q = l >> 4, ln = l & 15;

  // ---- generate A[n][d] = tanh(pe[m,d] + pd[n,d]) into swizzled LDS ----
  // wave w owns rows w*4..w*4+3; lane l owns d = l*8..l*8+7 (coalesced)
  {
    const float* per = pe + (size_t)blk * 512 + l * 8;
    const float4 pe0 = *(const float4*)(per);
    const float4 pe1 = *(const float4*)(per + 4);
#pragma unroll
    for (int r = 0; r < 4; ++r) {
      const int n = (w << 2) | r;
      const float* pdr = pd + (size_t)((b << 6) | n) * 512 + l * 8;
      const float4 q0 = *(const float4*)(pdr);
      const float4 q1 = *(const float4*)(pdr + 4);
      float x[8] = {pe0.x + q0.x, pe0.y + q0.y, pe0.z + q0.z, pe0.w + q0.w,
                    pe1.x + q1.x, pe1.y + q1.y, pe1.z + q1.z, pe1.w + q1.w};
      u16x8 pk;
#pragma unroll
      for (int e = 0; e < 8; ++e) {
        const float ex = __expf(2.0f * x[e]);                    // tanh = 1 - 2/(e^2x+1)
        const float tv = 1.0f - 2.0f * __builtin_amdgcn_rcpf(ex + 1.0f);
        pk[e] = f2bf(tv);
      }
      *(u16x8*)((char*)A_sh + n * 1024 + ((l ^ (n & 7)) << 4)) = pk;
    }
  }
  __syncthreads();

  // ---- GEMM: wave w owns cols [w*64, w*64+64), rows 0..63 ----
  f32x4 acc[4][4];
#pragma unroll
  for (int rf = 0; rf < 4; ++rf)
#pragma unroll
    for (int cf = 0; cf < 4; ++cf) acc[rf][cf] = (f32x4){0.f, 0.f, 0.f, 0.f};

  const char* Abase = (const char*)A_sh + ln * 1024;   // + rf*16384, row = rf*16+ln
  const unsigned short* Wb = W2B + (size_t)(w * 64 + ln) * 512 + q * 8;  // + cf*8192 + ks*32
  const int xr = ln & 7;                                // row&7 == ln&7

  for (int ks = 0; ks < 16; ++ks) {
    u16x8 bv[4], av[4];
#pragma unroll
    for (int cf = 0; cf < 4; ++cf)
      bv[cf] = *(const u16x8*)(Wb + cf * 8192 + ks * 32);
#pragma unroll
    for (int rf = 0; rf < 4; ++rf)
      av[rf] = *(const u16x8*)(Abase + rf * 16384 + (((ks * 4 + q) ^ xr) << 4));
#pragma unroll
    for (int rf = 0; rf < 4; ++rf)
#pragma unroll
      for (int cf = 0; cf < 4; ++cf)
        acc[rf][cf] = mfma16(av[rf], bv[cf], acc[rf][cf]);
  }

  // ---- epilogue: logits = acc + b2 (sum in log2 domain) ----
  // thread's elements: rows rf*16 + q*4 + j (16), cols w*64 + cf*16 + ln (4)
  const float L2E = 1.4426950408889634f;   // log2(e)
  const float LN2 = 0.6931471805599453f;
  float b2v[4];
#pragma unroll
  for (int cf = 0; cf < 4; ++cf) b2v[cf] = b2[w * 64 + cf * 16 + ln];
#pragma unroll
  for (int rf = 0; rf < 4; ++rf)
#pragma unroll
    for (int cf = 0; cf < 4; ++cf)
#pragma unroll
      for (int j = 0; j < 4; ++j) acc[rf][cf][j] += b2v[cf];

  // per-wave partial sum of 2^(x*log2e) over this wave's 64 cols, per row
  {
    float sm[4][4];
#pragma unroll
    for (int rf = 0; rf < 4; ++rf)
#pragma unroll
      for (int j = 0; j < 4; ++j) {
        float s = 0.f;
#pragma unroll
        for (int cf = 0; cf < 4; ++cf)
          s += __builtin_amdgcn_exp2f(acc[rf][cf][j] * L2E);   // v_exp_f32
        sm[rf][j] = s;
      }
#pragma unroll
    for (int o = 1; o < 16; o <<= 1)
#pragma unroll
      for (int rf = 0; rf < 4; ++rf)
#pragma unroll
        for (int j = 0; j < 4; ++j)
          sm[rf][j] += __shfl_xor(sm[rf][j], o);
    if (ln == 0) {
#pragma unroll
      for (int rf = 0; rf < 4; ++rf)
#pragma unroll
        for (int j = 0; j < 4; ++j)
          red[rf * 16 + q * 4 + j][w] = sm[rf][j];
    }
  }
  __syncthreads();

  // merge the 16 wave-partials: thread tid<64 handles row tid
  if (tid < 64) {
    float s = red[tid][0];
#pragma unroll
    for (int ww = 1; ww < 16; ++ww) s += red[tid][ww];
    lse_sh[tid] = LN2 * __builtin_amdgcn_logf(s);   // v_log_f32 = log2
  }
  __syncthreads();

  // final: out = acc - lse  (nontemporal: never re-read; keep L2 for W2)
  float* outb = out + (size_t)blk * 65536 + w * 64 + ln;
#pragma unroll
  for (int rf = 0; rf < 4; ++rf)
#pragma unroll
    for (int j = 0; j < 4; ++j) {
      const int row = rf * 16 + q * 4 + j;
      const float lse = lse_sh[row];
      float* orow = outb + (size_t)row * 1024;
#pragma unroll
      for (int cf = 0; cf < 4; ++cf)
        __builtin_nontemporal_store(acc[rf][cf][j] - lse, orow + cf * 16);
    }
}

extern "C" void kernel_launch(void* const* d_in, const int* in_sizes, int n_in,
                              void* d_out, int out_size, void* d_ws, size_t ws_size,
                              hipStream_t stream) {
  (void)in_sizes; (void)n_in; (void)out_size; (void)ws_size;
  const float* enc = (const float*)d_in[0];
  const float* dec = (const float*)d_in[1];
  const float* W1  = (const float*)d_in[2];
  const float* b1  = (const float*)d_in[3];
  const float* W2  = (const float*)d_in[4];
  const float* b2  = (const float*)d_in[5];
  float* out = (float*)d_out;

  char* ws = (char*)d_ws;
  unsigned short* encB = (unsigned short*)(ws + 0);        // 1 MiB   (524288 el)
  unsigned short* decB = (unsigned short*)(ws + 1048576);  // 256 KiB (131072 el)
  unsigned short* W1eB = (unsigned short*)(ws + 1310720);  // 512 KiB (262144 el)
  unsigned short* W1dB = (unsigned short*)(ws + 1835008);  // 512 KiB (262144 el)
  unsigned short* W2B  = (unsigned short*)(ws + 2359296);  // 1 MiB   (524288 el)
  float*          pe   = (float*)(ws + 3407872);           // 2 MiB  [1024][512]
  float*          pd   = (float*)(ws + 5505024);           // 512 KiB [256][512]

  prep_kernel<<<2048, 256, 0, stream>>>(enc, dec, W1, W2, encB, decB, W1eB, W1dB, W2B);
  proj_kernel<<<128, 256, 0, stream>>>(encB, W1eB, nullptr, pe);   // pe: 1024x512
  proj_kernel<<< 32, 256, 0, stream>>>(decB, W1dB, b1,      pd);   // pd:  256x512
  joint_kernel<<<1024, 1024, 0, stream>>>(pe, pd, W2B, b2, out);
}

// Round 12
// 155.233 us; speedup vs baseline: 3.5551x; 1.4475x over previous
//
#include <hip/hip_runtime.h>
#include <hip/hip_bf16.h>
#include <stdint.h>

// B=4, M=256, N=64, D=512, C=1024
// out[b,m,n,c] = log_softmax_c( tanh(pe[b,m,:] + pd[b,n,:]) . W2[c,:] + b2[c] )
// pe = enc @ W1[:, :D]^T ; pd = dec @ W1[:, D:]^T + b1
// log_softmax WITHOUT the max pass (logits bounded ~18 -> f32-safe).
// W2 re-tiled in prep to MFMA-native order so every B-fragment load is a
// fully-coalesced 1KB wave transaction (was: 64 lanes x 16B at 1KB stride
// = 64 cache lines per instruction).

typedef __bf16         bf16x8 __attribute__((ext_vector_type(8)));
typedef float          f32x4  __attribute__((ext_vector_type(4)));
typedef unsigned short u16x8  __attribute__((ext_vector_type(8)));

__device__ __forceinline__ unsigned short f2bf(float f) {
  unsigned int u = __float_as_uint(f);
  u += 0x7fffu + ((u >> 16) & 1u);          // RNE
  return (unsigned short)(u >> 16);
}

__device__ __forceinline__ f32x4 mfma16(u16x8 a, u16x8 b, f32x4 c) {
  return __builtin_amdgcn_mfma_f32_16x16x32_bf16(
      __builtin_bit_cast(bf16x8, a), __builtin_bit_cast(bf16x8, b), c, 0, 0, 0);
}

// ---------------- prep: f32 -> bf16 conversions + W2 tiling ----------------
// W2s layout: i = ((((colblk*16 + ks)*4 + cf)*16 + ln)*4 + q)*8 + e
//   col = colblk*64 + cf*16 + ln   (0..1023)
//   k   = ks*32 + q*8 + e          (0..511)
__global__ __launch_bounds__(256) void prep_kernel(
    const float* __restrict__ enc, const float* __restrict__ dec,
    const float* __restrict__ W1,  const float* __restrict__ W2,
    unsigned short* __restrict__ encB, unsigned short* __restrict__ decB,
    unsigned short* __restrict__ W1eB, unsigned short* __restrict__ W1dB,
    unsigned short* __restrict__ W2s)
{
  const int i = blockIdx.x * 256 + threadIdx.x;   // 0 .. 524287
  encB[i] = f2bf(enc[i]);
  {
    const int e = i & 7, q = (i >> 3) & 3, ln = (i >> 5) & 15;
    const int cf = (i >> 9) & 3, ks = (i >> 11) & 15, cb = i >> 15;
    const int col = cb * 64 + cf * 16 + ln;
    const int k   = ks * 32 + q * 8 + e;
    W2s[i] = f2bf(W2[col * 512 + k]);
  }
  if (i < 262144) {                                // W1 is [512][1024]
    const int k = i >> 9, d = i & 511;
    W1eB[i] = f2bf(W1[k * 1024 + d]);
    W1dB[i] = f2bf(W1[k * 1024 + 512 + d]);
  }
  if (i < 131072) decB[i] = f2bf(dec[i]);
}

// ---------------- proj: out[r][c] = sum_d A[r][d]*Wt[c][d] (+bias[c]) ----------------
__global__ __launch_bounds__(256) void proj_kernel(
    const unsigned short* __restrict__ A, const unsigned short* __restrict__ Wt,
    const float* __restrict__ bias, float* __restrict__ out)
{
  const int rtile = blockIdx.x >> 3;
  const int ctile = blockIdx.x & 7;
  const int w = threadIdx.x >> 6;
  const int l = threadIdx.x & 63;
  const int q = l >> 4, ln = l & 15;

  f32x4 acc[4] = {};
  const unsigned short* Ab = A  + (size_t)(rtile * 64 + ln) * 512 + q * 8;
  const unsigned short* Wb = Wt + (size_t)(ctile * 64 + w * 16 + ln) * 512 + q * 8;

#pragma unroll 4
  for (int ks = 0; ks < 16; ++ks) {
    u16x8 bv = *(const u16x8*)(Wb + ks * 32);
#pragma unroll
    for (int rf = 0; rf < 4; ++rf) {
      u16x8 av = *(const u16x8*)(Ab + rf * 16 * 512 + ks * 32);
      acc[rf] = mfma16(av, bv, acc[rf]);
    }
  }
  const int col = ctile * 64 + w * 16 + ln;
  const float bv = bias ? bias[col] : 0.0f;
#pragma unroll
  for (int rf = 0; rf < 4; ++rf)
#pragma unroll
    for (int j = 0; j < 4; ++j)
      out[(size_t)(rtile * 64 + rf * 16 + q * 4 + j) * 512 + col] = acc[rf][j] + bv;
}

// ---------------- joint: fused tanh-GEMM + bias + log_softmax (no-max) ----------------
// grid = B*M = 1024 blocks, block = 1024 threads (16 waves).
// Wave w: all 64 rows x cols [w*64, w*64+64). acc = 4x4 f32x4 = 64 f32/thread.
__global__ __launch_bounds__(1024) void joint_kernel(
    const float* __restrict__ pe, const float* __restrict__ pd,
    const unsigned short* __restrict__ W2s, const float* __restrict__ b2,
    float* __restrict__ out)
{
  __shared__ unsigned short A_sh[64 * 512];   // 64 KiB, XOR-swizzled bf16 tile
  __shared__ float red[64][17];               // per-row, per-wave sum2exp (padded)
  __shared__ float lse_sh[64];

  const int blk = blockIdx.x;            // b*256 + m
  const int b   = blk >> 8;
  const int tid = threadIdx.x;
  const int w = tid >> 6, l = tid & 63;
  const int q = l >> 4, ln = l & 15;

  // ---- generate A[n][d] = tanh(pe[m,d] + pd[n,d]) into swizzled LDS ----
  // wave w owns rows w*4..w*4+3; lane l owns d = l*8..l*8+7 (coalesced)
  {
    const float* per = pe + (size_t)blk * 512 + l * 8;
    const float4 pe0 = *(const float4*)(per);
    const float4 pe1 = *(const float4*)(per + 4);
#pragma unroll
    for (int r = 0; r < 4; ++r) {
      const int n = (w << 2) | r;
      const float* pdr = pd + (size_t)((b << 6) | n) * 512 + l * 8;
      const float4 q0 = *(const float4*)(pdr);
      const float4 q1 = *(const float4*)(pdr + 4);
      float x[8] = {pe0.x + q0.x, pe0.y + q0.y, pe0.z + q0.z, pe0.w + q0.w,
                    pe1.x + q1.x, pe1.y + q1.y, pe1.z + q1.z, pe1.w + q1.w};
      u16x8 pk;
#pragma unroll
      for (int e = 0; e < 8; ++e) {
        const float ex = __expf(2.0f * x[e]);                    // tanh = 1 - 2/(e^2x+1)
        const float tv = 1.0f - 2.0f * __builtin_amdgcn_rcpf(ex + 1.0f);
        pk[e] = f2bf(tv);
      }
      *(u16x8*)((char*)A_sh + n * 1024 + ((l ^ (n & 7)) << 4)) = pk;
    }
  }
  __syncthreads();

  // ---- GEMM: wave w owns cols [w*64, w*64+64), rows 0..63 ----
  f32x4 acc[4][4];
#pragma unroll
  for (int rf = 0; rf < 4; ++rf)
#pragma unroll
    for (int cf = 0; cf < 4; ++cf) acc[rf][cf] = (f32x4){0.f, 0.f, 0.f, 0.f};

  const char* Abase = (const char*)A_sh + ln * 1024;   // + rf*16384, row = rf*16+ln
  // coalesced B: wave w streams W2s[w*32768 .. +32768) sequentially
  const unsigned short* Wb = W2s + (size_t)w * 32768 + ((ln * 4 + q) * 8);
  const int xr = ln & 7;                                // row&7 == ln&7

  for (int ks = 0; ks < 16; ++ks) {
    u16x8 bv[4], av[4];
#pragma unroll
    for (int cf = 0; cf < 4; ++cf)
      bv[cf] = *(const u16x8*)(Wb + (ks * 4 + cf) * 512);
#pragma unroll
    for (int rf = 0; rf < 4; ++rf)
      av[rf] = *(const u16x8*)(Abase + rf * 16384 + (((ks * 4 + q) ^ xr) << 4));
#pragma unroll
    for (int rf = 0; rf < 4; ++rf)
#pragma unroll
      for (int cf = 0; cf < 4; ++cf)
        acc[rf][cf] = mfma16(av[rf], bv[cf], acc[rf][cf]);
  }

  // ---- epilogue: logits = acc + b2 (sum in log2 domain) ----
  // thread's elements: rows rf*16 + q*4 + j (16), cols w*64 + cf*16 + ln (4)
  const float L2E = 1.4426950408889634f;   // log2(e)
  const float LN2 = 0.6931471805599453f;
  float b2v[4];
#pragma unroll
  for (int cf = 0; cf < 4; ++cf) b2v[cf] = b2[w * 64 + cf * 16 + ln];
#pragma unroll
  for (int rf = 0; rf < 4; ++rf)
#pragma unroll
    for (int cf = 0; cf < 4; ++cf)
#pragma unroll
      for (int j = 0; j < 4; ++j) acc[rf][cf][j] += b2v[cf];

  // per-wave partial sum of 2^(x*log2e) over this wave's 64 cols, per row
  {
    float sm[4][4];
#pragma unroll
    for (int rf = 0; rf < 4; ++rf)
#pragma unroll
      for (int j = 0; j < 4; ++j) {
        float s = 0.f;
#pragma unroll
        for (int cf = 0; cf < 4; ++cf)
          s += __builtin_amdgcn_exp2f(acc[rf][cf][j] * L2E);   // v_exp_f32
        sm[rf][j] = s;
      }
#pragma unroll
    for (int o = 1; o < 16; o <<= 1)
#pragma unroll
      for (int rf = 0; rf < 4; ++rf)
#pragma unroll
        for (int j = 0; j < 4; ++j)
          sm[rf][j] += __shfl_xor(sm[rf][j], o);
    if (ln == 0) {
#pragma unroll
      for (int rf = 0; rf < 4; ++rf)
#pragma unroll
        for (int j = 0; j < 4; ++j)
          red[rf * 16 + q * 4 + j][w] = sm[rf][j];
    }
  }
  __syncthreads();

  // merge the 16 wave-partials: thread tid<64 handles row tid
  if (tid < 64) {
    float s = red[tid][0];
#pragma unroll
    for (int ww = 1; ww < 16; ++ww) s += red[tid][ww];
    lse_sh[tid] = LN2 * __builtin_amdgcn_logf(s);   // v_log_f32 = log2
  }
  __syncthreads();

  // final: out = acc - lse  (regular stores: L2 write-combines partial lines)
  float* outb = out + (size_t)blk * 65536 + w * 64 + ln;
#pragma unroll
  for (int rf = 0; rf < 4; ++rf)
#pragma unroll
    for (int j = 0; j < 4; ++j) {
      const int row = rf * 16 + q * 4 + j;
      const float lse = lse_sh[row];
      float* orow = outb + (size_t)row * 1024;
#pragma unroll
      for (int cf = 0; cf < 4; ++cf) orow[cf * 16] = acc[rf][cf][j] - lse;
    }
}

extern "C" void kernel_launch(void* const* d_in, const int* in_sizes, int n_in,
                              void* d_out, int out_size, void* d_ws, size_t ws_size,
                              hipStream_t stream) {
  (void)in_sizes; (void)n_in; (void)out_size; (void)ws_size;
  const float* enc = (const float*)d_in[0];
  const float* dec = (const float*)d_in[1];
  const float* W1  = (const float*)d_in[2];
  const float* b1  = (const float*)d_in[3];
  const float* W2  = (const float*)d_in[4];
  const float* b2  = (const float*)d_in[5];
  float* out = (float*)d_out;

  char* ws = (char*)d_ws;
  unsigned short* encB = (unsigned short*)(ws + 0);        // 1 MiB   (524288 el)
  unsigned short* decB = (unsigned short*)(ws + 1048576);  // 256 KiB (131072 el)
  unsigned short* W1eB = (unsigned short*)(ws + 1310720);  // 512 KiB (262144 el)
  unsigned short* W1dB = (unsigned short*)(ws + 1835008);  // 512 KiB (262144 el)
  unsigned short* W2s  = (unsigned short*)(ws + 2359296);  // 1 MiB   (524288 el, tiled)
  float*          pe   = (float*)(ws + 3407872);           // 2 MiB  [1024][512]
  float*          pd   = (float*)(ws + 5505024);           // 512 KiB [256][512]

  prep_kernel<<<2048, 256, 0, stream>>>(enc, dec, W1, W2, encB, decB, W1eB, W1dB, W2s);
  proj_kernel<<<128, 256, 0, stream>>>(encB, W1eB, nullptr, pe);   // pe: 1024x512
  proj_kernel<<< 32, 256, 0, stream>>>(decB, W1dB, b1,      pd);   // pd:  256x512
  joint_kernel<<<1024, 1024, 0, stream>>>(pe, pd, W2s, b2, out);
}